// Round 1
// baseline (127.954 us; speedup 1.0000x reference)
//
#include <hip/hip_runtime.h>
#include <math.h>

// Problem constants (from reference setup_inputs)
#define TEMP 0.07f
constexpr int B = 2048;
constexpr int V = 2;
constexpr int D = 256;
constexpr int C = 1000;
constexpr int N = V * B;  // 4096

typedef __attribute__((ext_vector_type(8))) short bf16x8;   // 8 bf16 (4 VGPRs)
typedef __attribute__((ext_vector_type(4))) float floatx4;  // MFMA accumulator

__device__ __forceinline__ short f2bf(float x) {
  union { float f; unsigned u; } v; v.f = x;
  unsigned r = v.u + 0x7FFF + ((v.u >> 16) & 1);  // round-to-nearest-even
  return (short)(r >> 16);
}

// Kernel 1: L2-normalize each (b,v) feature row, write bf16 cf[v*B+b][D]
// One wave per row: 64 lanes x float4 = 256 elements.
__global__ __launch_bounds__(256) void normalize_kernel(
    const float* __restrict__ feat, short* __restrict__ cf) {
  int wave = (blockIdx.x << 2) | (threadIdx.x >> 6);  // [0, 4096)
  int lane = threadIdx.x & 63;
  int i = wave;              // i = v*B + b
  int v = i >> 11;           // / B
  int b = i & (B - 1);
  const float* src = feat + (size_t)(b * V + v) * D;
  float4 x = ((const float4*)src)[lane];
  float ss = x.x * x.x + x.y * x.y + x.z * x.z + x.w * x.w;
  #pragma unroll
  for (int m = 32; m; m >>= 1) ss += __shfl_xor(ss, m);
  float inv = rsqrtf(ss);
  short4 o;
  o.x = f2bf(x.x * inv); o.y = f2bf(x.y * inv);
  o.z = f2bf(x.z * inv); o.w = f2bf(x.w * inv);
  ((short4*)(cf + (size_t)i * D))[lane] = o;
}

// Kernel 2: per-sample focal modulation (1-pt)^2 and same-label counts.
// One wave per b.
__global__ __launch_bounds__(256) void mod_cnt_kernel(
    const float* __restrict__ preds, const int* __restrict__ labels,
    float* __restrict__ modv, int* __restrict__ cnt) {
  int b = (blockIdx.x << 2) | (threadIdx.x >> 6);  // [0, 2048)
  int lane = threadIdx.x & 63;
  const float* p = preds + (size_t)b * C;
  float m = -1e30f;
  for (int j = lane; j < C; j += 64) m = fmaxf(m, p[j]);
  #pragma unroll
  for (int mk = 32; mk; mk >>= 1) m = fmaxf(m, __shfl_xor(m, mk));
  float s = 0.f;
  for (int j = lane; j < C; j += 64) s += __expf(p[j] - m);
  #pragma unroll
  for (int mk = 32; mk; mk >>= 1) s += __shfl_xor(s, mk);
  int lab = labels[b];
  float nll = p[lab] - (m + logf(s));  // log p_t
  float pt = __expf(nll);
  float md = 1.f - pt; md = md * md;   // gamma = 2
  int c = 0;
  for (int j = lane; j < B; j += 64) c += (labels[j] == lab) ? 1 : 0;
  #pragma unroll
  for (int mk = 32; mk; mk >>= 1) c += __shfl_xor(c, mk);
  if (lane == 0) { modv[b] = md; cnt[b] = c; }
}

// Kernel 3: Gram matrix S = cf*cf^T / T, fused epilogue.
// Per row i accumulate: Z[i] = sum_{j!=i} exp(s_ij - 1/T)
//                       P[i] = sum_{j!=i, label match} s_ij
// Block = 128x128 tile, 4 waves in 2x2, each wave 64x64 via 4x4 MFMA
// 16x16x32 bf16 tiles. Fragments loaded directly from global (cf = 2MB,
// L2-resident).
__global__ __launch_bounds__(256) void gram_kernel(
    const short* __restrict__ cf, const int* __restrict__ labels,
    float* __restrict__ Z, float* __restrict__ P) {
  const int lane = threadIdx.x & 63;
  const int wave = threadIdx.x >> 6;
  const int row_base = blockIdx.y * 128 + (wave >> 1) * 64;
  const int col_base = blockIdx.x * 128 + (wave & 1) * 64;
  const int l16 = lane & 15;
  const int quad = lane >> 4;
  const int koff = quad * 8;

  floatx4 acc[4][4] = {};

  for (int ko = 0; ko < D; ko += 32) {
    bf16x8 a[4], bb[4];
    #pragma unroll
    for (int t = 0; t < 4; ++t)
      a[t] = *(const bf16x8*)(cf + (size_t)(row_base + t * 16 + l16) * D + ko + koff);
    #pragma unroll
    for (int t = 0; t < 4; ++t)
      bb[t] = *(const bf16x8*)(cf + (size_t)(col_base + t * 16 + l16) * D + ko + koff);
    #pragma unroll
    for (int rt = 0; rt < 4; ++rt)
      #pragma unroll
      for (int ct = 0; ct < 4; ++ct)
        acc[rt][ct] = __builtin_amdgcn_mfma_f32_16x16x32_bf16(a[rt], bb[ct], acc[rt][ct], 0, 0, 0);
  }

  // Epilogue. C/D layout (m89-verified): col = lane&15, row = quad*4 + reg.
  const float invT = 1.0f / TEMP;  // also the fixed LSE shift K (s_ij <= 1/T)
  int clab[4], colg[4];
  #pragma unroll
  for (int ct = 0; ct < 4; ++ct) {
    colg[ct] = col_base + ct * 16 + l16;
    clab[ct] = labels[colg[ct] & (B - 1)];
  }
  #pragma unroll
  for (int rt = 0; rt < 4; ++rt) {
    #pragma unroll
    for (int r = 0; r < 4; ++r) {
      int row = row_base + rt * 16 + quad * 4 + r;
      int rlab = labels[row & (B - 1)];
      float zs = 0.f, ps = 0.f;
      #pragma unroll
      for (int ct = 0; ct < 4; ++ct) {
        float sv = acc[rt][ct][r] * invT;
        if (colg[ct] != row) {
          zs += __expf(sv - invT);
          if (clab[ct] == rlab) ps += sv;
        }
      }
      // reduce across the 16 lanes holding this row (xor masks stay in-group)
      #pragma unroll
      for (int mk = 1; mk < 16; mk <<= 1) {
        zs += __shfl_xor(zs, mk);
        ps += __shfl_xor(ps, mk);
      }
      if (l16 == 0) {
        atomicAdd(&Z[row], zs);
        atomicAdd(&P[row], ps);
      }
    }
  }
}

// Kernel 4: final reduction over 4096 rows -> scalar loss.
__global__ __launch_bounds__(256) void finalize_kernel(
    const float* __restrict__ Z, const float* __restrict__ P,
    const float* __restrict__ modv, const int* __restrict__ cnt,
    float* __restrict__ out) {
  __shared__ float red[4];
  int tid = threadIdx.x;
  float acc = 0.f;
  for (int i = tid; i < N; i += 256) {
    int b = i & (B - 1);
    float c = (float)(2 * cnt[b] - 1);  // positives excluding self; >= 1
    float lse = (1.0f / TEMP) + logf(Z[i]);
    acc += modv[b] * (P[i] - c * lse) / c;
  }
  #pragma unroll
  for (int m = 32; m; m >>= 1) acc += __shfl_xor(acc, m);
  if ((tid & 63) == 0) red[tid >> 6] = acc;
  __syncthreads();
  if (tid == 0) out[0] = -(red[0] + red[1] + red[2] + red[3]) / (float)N;
}

extern "C" void kernel_launch(void* const* d_in, const int* in_sizes, int n_in,
                              void* d_out, int out_size, void* d_ws, size_t ws_size,
                              hipStream_t stream) {
  const float* feat = (const float*)d_in[0];   // [B, V, D] fp32
  const float* preds = (const float*)d_in[1];  // [B, C] fp32
  const int* labels = (const int*)d_in[2];     // [B] int32
  float* out = (float*)d_out;

  char* ws = (char*)d_ws;
  float* Z    = (float*)(ws);           // 4096 f32 = 16 KB
  float* P    = (float*)(ws + 16384);   // 4096 f32 = 16 KB
  float* modv = (float*)(ws + 32768);   // 2048 f32 = 8 KB
  int*   cnt  = (int*)  (ws + 40960);   // 2048 i32 = 8 KB
  short* cf   = (short*)(ws + 49152);   // 4096*256 bf16 = 2 MB

  // Z and P must start at zero (ws is poisoned before every launch)
  hipMemsetAsync(ws, 0, 32768, stream);

  normalize_kernel<<<1024, 256, 0, stream>>>(feat, cf);
  mod_cnt_kernel<<<512, 256, 0, stream>>>(preds, labels, modv, cnt);
  dim3 grid(N / 128, N / 128);  // 32 x 32
  gram_kernel<<<grid, 256, 0, stream>>>(cf, labels, Z, P);
  finalize_kernel<<<1, 256, 0, stream>>>(Z, P, modv, cnt, out);
}